// Round 5
// baseline (383.960 us; speedup 1.0000x reference)
//
#include <hip/hip_runtime.h>
#include <hip/hip_bf16.h>
#include <stdint.h>
#include <stddef.h>

#define S_LEN 4096
#define DMODEL 1024
#define NHEAD 16
#define HDIM 64
#define L2E 1.4426950408889634f

typedef __attribute__((ext_vector_type(8))) short bf16x8;
typedef __attribute__((ext_vector_type(8))) unsigned short u16x8;
typedef __attribute__((ext_vector_type(4))) float f32x4;

__device__ __forceinline__ unsigned short f2bf(float f) {
    unsigned int u = __float_as_uint(f);
    return (unsigned short)((u + 0x7FFFu + ((u >> 16) & 1u)) >> 16);
}

// ---------------- RoPE table: cos/sin [4096][32] ----------------
__global__ __launch_bounds__(256) void rope_table_kernel(float* __restrict__ ctab,
                                                         float* __restrict__ stab) {
    int i = blockIdx.x * 256 + threadIdx.x;
    int s = i >> 5, j = i & 31;
    float freq = exp2f(-0.41524101186092407f * (float)j);   // 10000^(-j/32)
    float ang = (float)s * freq;
    ctab[i] = cosf(ang);
    stab[i] = sinf(ang);
}

// ---------------- W [K][N] f32 -> Wt [N][K] bf16 (transpose) ----------------
__global__ __launch_bounds__(256) void cvt_wt_kernel(
    const float* __restrict__ w0, const float* __restrict__ w1,
    const float* __restrict__ w2, const float* __restrict__ w3,
    unsigned short* __restrict__ t0, unsigned short* __restrict__ t1,
    unsigned short* __restrict__ t2, unsigned short* __restrict__ t3) {
    const float* src; unsigned short* dst;
    switch (blockIdx.z) {
        case 0: src = w0; dst = t0; break;
        case 1: src = w1; dst = t1; break;
        case 2: src = w2; dst = t2; break;
        default: src = w3; dst = t3; break;
    }
    __shared__ float tile[64][65];
    int t = threadIdx.x;
    int k0 = blockIdx.y * 64, n0 = blockIdx.x * 64;
    int r = t >> 2, q4 = (t & 3) * 16;
    const float* sp = src + (size_t)(k0 + r) * DMODEL + n0 + q4;
    #pragma unroll
    for (int j = 0; j < 4; ++j) {
        f32x4 v = *(const f32x4*)(sp + j * 4);
        #pragma unroll
        for (int e = 0; e < 4; ++e) tile[r][q4 + j * 4 + e] = v[e];
    }
    __syncthreads();
    int n = t >> 2, kq = (t & 3) * 16;
    unsigned short* dp = dst + (size_t)(n0 + n) * DMODEL + k0 + kq;
    u16x8 a, b;
    #pragma unroll
    for (int j = 0; j < 8; ++j) { a[j] = f2bf(tile[kq + j][n]); b[j] = f2bf(tile[kq + 8 + j][n]); }
    *(u16x8*)dp = a;
    *(u16x8*)(dp + 8) = b;
}

// ---------------- GEMM 128x128x64, 4 waves, 16x16x32 bf16 MFMA ----------------
// MODE 1: A = f32 (convert in-flight); z in {0,1,2} selects q/k/v output;
//         z<2 RoPE epilogue; z==0 scales by 0.125. bf16 stores.
// MODE 0: A = bf16 ctx; f32 store to fo (d_out).
template<int MODE>
__global__ __launch_bounds__(256) void gemm_kernel(
    const float* __restrict__ Af,
    const unsigned short* __restrict__ Ab,
    const unsigned short* __restrict__ B0,
    const unsigned short* __restrict__ B1,
    const unsigned short* __restrict__ B2,
    unsigned short* __restrict__ o0,
    unsigned short* __restrict__ o1,
    unsigned short* __restrict__ o2,
    float* __restrict__ fo,
    const float* __restrict__ ctab,
    const float* __restrict__ stab) {
    int z = blockIdx.z;
    const unsigned short* Bt = (MODE == 0) ? B0 : (z == 0 ? B0 : (z == 1 ? B1 : B2));
    unsigned short* outp     = (MODE == 0) ? o0 : (z == 0 ? o0 : (z == 1 ? o1 : o2));
    int m0 = blockIdx.y * 128, n0 = blockIdx.x * 128;
    __shared__ unsigned short As[128][72];
    __shared__ unsigned short Bs[128][72];
    int t = threadIdx.x, w = t >> 6, l = t & 63;
    int wm = w >> 1, wn = w & 1, g = l >> 4, c = l & 15;

    f32x4 acc[4][4];
    #pragma unroll
    for (int m = 0; m < 4; ++m)
        #pragma unroll
        for (int n = 0; n < 4; ++n) acc[m][n] = (f32x4){0.f, 0.f, 0.f, 0.f};

    int sr = t >> 1, scc = (t & 1) * 32;

    for (int kt = 0; kt < DMODEL; kt += 64) {
        __syncthreads();
        if (MODE == 1) {
            const float* gp = Af + (size_t)(m0 + sr) * DMODEL + kt + scc;
            #pragma unroll
            for (int j = 0; j < 4; ++j) {
                f32x4 lo = *(const f32x4*)(gp + j * 8);
                f32x4 hi = *(const f32x4*)(gp + j * 8 + 4);
                u16x8 o;
                #pragma unroll
                for (int e = 0; e < 4; ++e) { o[e] = f2bf(lo[e]); o[4 + e] = f2bf(hi[e]); }
                *(u16x8*)&As[sr][scc + j * 8] = o;
            }
        } else {
            const unsigned short* gp = Ab + (size_t)(m0 + sr) * DMODEL + kt + scc;
            #pragma unroll
            for (int j = 0; j < 4; ++j)
                *(u16x8*)&As[sr][scc + j * 8] = *(const u16x8*)(gp + j * 8);
        }
        {
            const unsigned short* gp = Bt + (size_t)(n0 + sr) * DMODEL + kt + scc;
            #pragma unroll
            for (int j = 0; j < 4; ++j)
                *(u16x8*)&Bs[sr][scc + j * 8] = *(const u16x8*)(gp + j * 8);
        }
        __syncthreads();
        #pragma unroll
        for (int kk = 0; kk < 64; kk += 32) {
            bf16x8 af[4], bf[4];
            #pragma unroll
            for (int m = 0; m < 4; ++m) af[m] = *(const bf16x8*)&As[wm * 64 + m * 16 + c][kk + g * 8];
            #pragma unroll
            for (int n = 0; n < 4; ++n) bf[n] = *(const bf16x8*)&Bs[wn * 64 + n * 16 + c][kk + g * 8];
            #pragma unroll
            for (int m = 0; m < 4; ++m)
                #pragma unroll
                for (int n = 0; n < 4; ++n)
                    acc[m][n] = __builtin_amdgcn_mfma_f32_16x16x32_bf16(af[m], bf[n], acc[m][n], 0, 0, 0);
        }
    }

    if (MODE == 1 && z < 2) {
        float sc8 = (z == 0) ? 0.125f : 1.0f;   // fold 1/sqrt(64) into q
        #pragma unroll
        for (int m = 0; m < 4; ++m) {
            #pragma unroll
            for (int r = 0; r < 4; ++r) {
                int srow = m0 + wm * 64 + m * 16 + g * 4 + r;
                #pragma unroll
                for (int n = 0; n < 2; ++n) {
                    int e = n * 16 + c;                      // e < 32 within head
                    float cs = ctab[srow * 32 + e];
                    float sn = stab[srow * 32 + e];
                    float lo = acc[m][n][r], hi = acc[m][n + 2][r];
                    float nlo = (lo * cs - hi * sn) * sc8;
                    float nhi = (hi * cs + lo * sn) * sc8;
                    size_t base = (size_t)srow * DMODEL + n0 + wn * 64;
                    outp[base + n * 16 + c]       = f2bf(nlo);
                    outp[base + (n + 2) * 16 + c] = f2bf(nhi);
                }
            }
        }
    } else if (MODE == 1) {
        #pragma unroll
        for (int m = 0; m < 4; ++m)
            #pragma unroll
            for (int r = 0; r < 4; ++r) {
                int srow = m0 + wm * 64 + m * 16 + g * 4 + r;
                size_t base = (size_t)srow * DMODEL + n0 + wn * 64;
                #pragma unroll
                for (int n = 0; n < 4; ++n)
                    outp[base + n * 16 + c] = f2bf(acc[m][n][r]);
            }
    } else {
        // f32 store to d_out
        #pragma unroll
        for (int m = 0; m < 4; ++m)
            #pragma unroll
            for (int r = 0; r < 4; ++r) {
                int srow = m0 + wm * 64 + m * 16 + g * 4 + r;
                size_t base = (size_t)srow * DMODEL + n0 + wn * 64;
                #pragma unroll
                for (int n = 0; n < 4; ++n)
                    fo[base + n * 16 + c] = acc[m][n][r];
            }
    }
}

// ---------------- causal flash attention, 64 q-rows x head per block ----------------
__global__ __launch_bounds__(256) void attn_kernel(
    const unsigned short* __restrict__ q,
    const unsigned short* __restrict__ k,
    const unsigned short* __restrict__ v,
    unsigned short* __restrict__ ctx) {
    int qb = blockIdx.x, h = blockIdx.y;
    int t = threadIdx.x, w = t >> 6, l = t & 63, g = l >> 4, c = l & 15;

    __shared__ unsigned short Ks[64][72];
    __shared__ unsigned short Vt[64][72];
    __shared__ unsigned short Ps[4][16][72];

    bf16x8 qf[2];
    {
        int qrow = qb * 64 + w * 16 + c;
        const unsigned short* qp = q + (size_t)qrow * DMODEL + h * HDIM + g * 8;
        qf[0] = *(const bf16x8*)qp;
        qf[1] = *(const bf16x8*)(qp + 32);
    }

    f32x4 o[4];
    #pragma unroll
    for (int n = 0; n < 4; ++n) o[n] = (f32x4){0.f, 0.f, 0.f, 0.f};
    float mrow[4] = {-3.0e38f, -3.0e38f, -3.0e38f, -3.0e38f};
    float lsum[4] = {0.f, 0.f, 0.f, 0.f};

    int skr = t >> 2, skc = (t & 3) * 16;
    int svr = t & 63, svc = (t >> 6) * 16;

    int nt = qb + 1;
    for (int kt = 0; kt < nt; ++kt) {
        int kv0 = kt * 64;
        __syncthreads();
        {
            const unsigned short* gk = k + (size_t)(kv0 + skr) * DMODEL + h * HDIM + skc;
            u16x8 a = *(const u16x8*)gk;
            u16x8 b = *(const u16x8*)(gk + 8);
            *(u16x8*)&Ks[skr][skc] = a;
            *(u16x8*)&Ks[skr][skc + 8] = b;
        }
        {
            const unsigned short* gv = v + (size_t)(kv0 + svr) * DMODEL + h * HDIM + svc;
            u16x8 a = *(const u16x8*)gv;
            u16x8 b = *(const u16x8*)(gv + 8);
            #pragma unroll
            for (int j = 0; j < 8; ++j) {
                Vt[svc + j][svr]     = a[j];
                Vt[svc + 8 + j][svr] = b[j];
            }
        }
        __syncthreads();

        f32x4 sf[4];
        #pragma unroll
        for (int n = 0; n < 4; ++n) {
            sf[n] = (f32x4){0.f, 0.f, 0.f, 0.f};
            #pragma unroll
            for (int ks = 0; ks < 2; ++ks) {
                bf16x8 kf = *(const bf16x8*)&Ks[n * 16 + c][ks * 32 + g * 8];
                sf[n] = __builtin_amdgcn_mfma_f32_16x16x32_bf16(qf[ks], kf, sf[n], 0, 0, 0);
            }
        }

        bool diag = (kt == qb);
        #pragma unroll
        for (int r = 0; r < 4; ++r) {
            int rowg = qb * 64 + w * 16 + g * 4 + r;
            if (diag) {
                #pragma unroll
                for (int n = 0; n < 4; ++n) {
                    int key = kv0 + n * 16 + c;
                    if (key > rowg) sf[n][r] = -3.0e38f;
                }
            }
            float tmax = fmaxf(fmaxf(sf[0][r], sf[1][r]), fmaxf(sf[2][r], sf[3][r]));
            #pragma unroll
            for (int d2 = 1; d2 < 16; d2 <<= 1) tmax = fmaxf(tmax, __shfl_xor(tmax, d2, 64));
            float mnew = fmaxf(mrow[r], tmax);
            float alpha = exp2f((mrow[r] - mnew) * L2E);
            mrow[r] = mnew;
            float psum = 0.f;
            #pragma unroll
            for (int n = 0; n < 4; ++n) {
                float p = exp2f((sf[n][r] - mnew) * L2E);
                sf[n][r] = p;
                psum += p;
            }
            #pragma unroll
            for (int d2 = 1; d2 < 16; d2 <<= 1) psum += __shfl_xor(psum, d2, 64);
            lsum[r] = lsum[r] * alpha + psum;
            #pragma unroll
            for (int n = 0; n < 4; ++n) o[n][r] *= alpha;
        }

        #pragma unroll
        for (int n = 0; n < 4; ++n)
            #pragma unroll
            for (int r = 0; r < 4; ++r)
                Ps[w][g * 4 + r][n * 16 + c] = f2bf(sf[n][r]);
        __syncthreads();

        bf16x8 pf0 = *(const bf16x8*)&Ps[w][c][g * 8];
        bf16x8 pf1 = *(const bf16x8*)&Ps[w][c][32 + g * 8];
        #pragma unroll
        for (int n = 0; n < 4; ++n) {
            bf16x8 vf0 = *(const bf16x8*)&Vt[n * 16 + c][g * 8];
            bf16x8 vf1 = *(const bf16x8*)&Vt[n * 16 + c][32 + g * 8];
            o[n] = __builtin_amdgcn_mfma_f32_16x16x32_bf16(pf0, vf0, o[n], 0, 0, 0);
            o[n] = __builtin_amdgcn_mfma_f32_16x16x32_bf16(pf1, vf1, o[n], 0, 0, 0);
        }
    }

    #pragma unroll
    for (int r = 0; r < 4; ++r) {
        float inv = 1.0f / lsum[r];
        int srow = qb * 64 + w * 16 + g * 4 + r;
        size_t base = (size_t)srow * DMODEL + h * HDIM;
        #pragma unroll
        for (int n = 0; n < 4; ++n)
            ctx[base + n * 16 + c] = f2bf(o[n][r] * inv);
    }
}

extern "C" void kernel_launch(void* const* d_in, const int* in_sizes, int n_in,
                              void* d_out, int out_size, void* d_ws, size_t ws_size,
                              hipStream_t stream) {
    const float* x  = (const float*)d_in[0];
    // d_in[1] = causal mask (tril by construction) — unused
    const float* Wq = (const float*)d_in[2];
    const float* Wk = (const float*)d_in[3];
    const float* Wv = (const float*)d_in[4];
    const float* Wo = (const float*)d_in[5];

    // ws layout (peak 35 MB; ws >= 64 MB verified in rounds 3-4):
    //   [0,0.5M) ctab  [0.5M,1M) stab
    //   [1M,9M)  ctx  (overlays Wtq/Wtk/Wtv, dead after QKV gemm)
    //   [1M,3M) Wtq  [3M,5M) Wtk  [5M,7M) Wtv
    //   [9M,11M) Wto
    //   [11M,19M) kr  [19M,27M) vb  [27M,35M) qr
    char* ws = (char*)d_ws;
    float* ctab = (float*)(ws);
    float* stab = (float*)(ws + (512u << 10));
    unsigned short* ctx = (unsigned short*)(ws + (1u  << 20));
    unsigned short* Wtq = (unsigned short*)(ws + (1u  << 20));
    unsigned short* Wtk = (unsigned short*)(ws + (3u  << 20));
    unsigned short* Wtv = (unsigned short*)(ws + (5u  << 20));
    unsigned short* Wto = (unsigned short*)(ws + (9u  << 20));
    unsigned short* kr  = (unsigned short*)(ws + (11u << 20));
    unsigned short* vb  = (unsigned short*)(ws + (19u << 20));
    unsigned short* qr  = (unsigned short*)(ws + (27u << 20));

    rope_table_kernel<<<(S_LEN * 32) / 256, 256, 0, stream>>>(ctab, stab);
    cvt_wt_kernel<<<dim3(16, 16, 4), 256, 0, stream>>>(Wq, Wk, Wv, Wo, Wtq, Wtk, Wtv, Wto);
    gemm_kernel<1><<<dim3(8, 32, 3), 256, 0, stream>>>(x, nullptr, Wtq, Wtk, Wtv,
                                                       qr, kr, vb, nullptr, ctab, stab);
    attn_kernel<<<dim3(64, 16), 256, 0, stream>>>(qr, kr, vb, ctx);
    gemm_kernel<0><<<dim3(8, 32, 1), 256, 0, stream>>>(nullptr, ctx, Wto, nullptr, nullptr,
                                                       nullptr, nullptr, nullptr,
                                                       (float*)d_out, ctab, stab);
}

// Round 6
// 273.767 us; speedup vs baseline: 1.4025x; 1.4025x over previous
//
#include <hip/hip_runtime.h>
#include <hip/hip_bf16.h>
#include <stdint.h>
#include <stddef.h>

#define S_LEN 4096
#define DMODEL 1024
#define NHEAD 16
#define HDIM 64
#define L2E 1.4426950408889634f

typedef __attribute__((ext_vector_type(8))) short bf16x8;
typedef __attribute__((ext_vector_type(8))) unsigned short u16x8;
typedef __attribute__((ext_vector_type(4))) float f32x4;

__device__ __forceinline__ unsigned short f2bf(float f) {
    unsigned int u = __float_as_uint(f);
    return (unsigned short)((u + 0x7FFFu + ((u >> 16) & 1u)) >> 16);
}

// ---------------- RoPE table: cos/sin [4096][32] ----------------
__global__ __launch_bounds__(256) void rope_table_kernel(float* __restrict__ ctab,
                                                         float* __restrict__ stab) {
    int i = blockIdx.x * 256 + threadIdx.x;
    int s = i >> 5, j = i & 31;
    float freq = exp2f(-0.41524101186092407f * (float)j);   // 10000^(-j/32)
    float ang = (float)s * freq;
    ctab[i] = cosf(ang);
    stab[i] = sinf(ang);
}

// ---------------- W [K][N] f32 -> Wt [N][K] bf16 (transpose) ----------------
__global__ __launch_bounds__(256) void cvt_wt_kernel(
    const float* __restrict__ w0, const float* __restrict__ w1,
    const float* __restrict__ w2, const float* __restrict__ w3,
    unsigned short* __restrict__ t0, unsigned short* __restrict__ t1,
    unsigned short* __restrict__ t2, unsigned short* __restrict__ t3) {
    const float* src; unsigned short* dst;
    switch (blockIdx.z) {
        case 0: src = w0; dst = t0; break;
        case 1: src = w1; dst = t1; break;
        case 2: src = w2; dst = t2; break;
        default: src = w3; dst = t3; break;
    }
    __shared__ float tile[64][65];
    int t = threadIdx.x;
    int k0 = blockIdx.y * 64, n0 = blockIdx.x * 64;
    int r = t >> 2, q4 = (t & 3) * 16;
    const float* sp = src + (size_t)(k0 + r) * DMODEL + n0 + q4;
    #pragma unroll
    for (int j = 0; j < 4; ++j) {
        f32x4 v = *(const f32x4*)(sp + j * 4);
        #pragma unroll
        for (int e = 0; e < 4; ++e) tile[r][q4 + j * 4 + e] = v[e];
    }
    __syncthreads();
    int n = t >> 2, kq = (t & 3) * 16;
    unsigned short* dp = dst + (size_t)(n0 + n) * DMODEL + k0 + kq;
    u16x8 a, b;
    #pragma unroll
    for (int j = 0; j < 8; ++j) { a[j] = f2bf(tile[kq + j][n]); b[j] = f2bf(tile[kq + 8 + j][n]); }
    *(u16x8*)dp = a;
    *(u16x8*)(dp + 8) = b;
}

// ---------------- GEMM 128x128x64, 4 waves, 16x16x32 bf16 MFMA ----------------
// MODE 1: A = f32 (convert in-flight); z in {0,1,2} selects q/k/v output;
//         z<2 RoPE epilogue; z==0 scales by 0.125. bf16 stores.
// MODE 0: A = bf16 ctx; f32 store to fo (d_out).
template<int MODE>
__global__ __launch_bounds__(256) void gemm_kernel(
    const float* __restrict__ Af,
    const unsigned short* __restrict__ Ab,
    const unsigned short* __restrict__ B0,
    const unsigned short* __restrict__ B1,
    const unsigned short* __restrict__ B2,
    unsigned short* __restrict__ o0,
    unsigned short* __restrict__ o1,
    unsigned short* __restrict__ o2,
    float* __restrict__ fo,
    const float* __restrict__ ctab,
    const float* __restrict__ stab) {
    int z = blockIdx.z;
    const unsigned short* Bt = (MODE == 0) ? B0 : (z == 0 ? B0 : (z == 1 ? B1 : B2));
    unsigned short* outp     = (MODE == 0) ? o0 : (z == 0 ? o0 : (z == 1 ? o1 : o2));
    int m0 = blockIdx.y * 128, n0 = blockIdx.x * 128;
    __shared__ unsigned short As[128][72];
    __shared__ unsigned short Bs[128][72];
    int t = threadIdx.x, w = t >> 6, l = t & 63;
    int wm = w >> 1, wn = w & 1, g = l >> 4, c = l & 15;

    f32x4 acc[4][4];
    #pragma unroll
    for (int m = 0; m < 4; ++m)
        #pragma unroll
        for (int n = 0; n < 4; ++n) acc[m][n] = (f32x4){0.f, 0.f, 0.f, 0.f};

    int sr = t >> 1, scc = (t & 1) * 32;

    for (int kt = 0; kt < DMODEL; kt += 64) {
        __syncthreads();
        if (MODE == 1) {
            const float* gp = Af + (size_t)(m0 + sr) * DMODEL + kt + scc;
            #pragma unroll
            for (int j = 0; j < 4; ++j) {
                f32x4 lo = *(const f32x4*)(gp + j * 8);
                f32x4 hi = *(const f32x4*)(gp + j * 8 + 4);
                u16x8 o;
                #pragma unroll
                for (int e = 0; e < 4; ++e) { o[e] = f2bf(lo[e]); o[4 + e] = f2bf(hi[e]); }
                *(u16x8*)&As[sr][scc + j * 8] = o;
            }
        } else {
            const unsigned short* gp = Ab + (size_t)(m0 + sr) * DMODEL + kt + scc;
            #pragma unroll
            for (int j = 0; j < 4; ++j)
                *(u16x8*)&As[sr][scc + j * 8] = *(const u16x8*)(gp + j * 8);
        }
        {
            const unsigned short* gp = Bt + (size_t)(n0 + sr) * DMODEL + kt + scc;
            #pragma unroll
            for (int j = 0; j < 4; ++j)
                *(u16x8*)&Bs[sr][scc + j * 8] = *(const u16x8*)(gp + j * 8);
        }
        __syncthreads();
        #pragma unroll
        for (int kk = 0; kk < 64; kk += 32) {
            bf16x8 af[4], bf[4];
            #pragma unroll
            for (int m = 0; m < 4; ++m) af[m] = *(const bf16x8*)&As[wm * 64 + m * 16 + c][kk + g * 8];
            #pragma unroll
            for (int n = 0; n < 4; ++n) bf[n] = *(const bf16x8*)&Bs[wn * 64 + n * 16 + c][kk + g * 8];
            #pragma unroll
            for (int m = 0; m < 4; ++m)
                #pragma unroll
                for (int n = 0; n < 4; ++n)
                    acc[m][n] = __builtin_amdgcn_mfma_f32_16x16x32_bf16(af[m], bf[n], acc[m][n], 0, 0, 0);
        }
    }

    if (MODE == 1 && z < 2) {
        float sc8 = (z == 0) ? 0.125f : 1.0f;   // fold 1/sqrt(64) into q
        #pragma unroll
        for (int m = 0; m < 4; ++m) {
            #pragma unroll
            for (int r = 0; r < 4; ++r) {
                int srow = m0 + wm * 64 + m * 16 + g * 4 + r;
                #pragma unroll
                for (int n = 0; n < 2; ++n) {
                    int e = n * 16 + c;                      // e < 32 within head
                    float cs = ctab[srow * 32 + e];
                    float sn = stab[srow * 32 + e];
                    float lo = acc[m][n][r], hi = acc[m][n + 2][r];
                    float nlo = (lo * cs - hi * sn) * sc8;
                    float nhi = (hi * cs + lo * sn) * sc8;
                    size_t base = (size_t)srow * DMODEL + n0 + wn * 64;
                    outp[base + n * 16 + c]       = f2bf(nlo);
                    outp[base + (n + 2) * 16 + c] = f2bf(nhi);
                }
            }
        }
    } else if (MODE == 1) {
        #pragma unroll
        for (int m = 0; m < 4; ++m)
            #pragma unroll
            for (int r = 0; r < 4; ++r) {
                int srow = m0 + wm * 64 + m * 16 + g * 4 + r;
                size_t base = (size_t)srow * DMODEL + n0 + wn * 64;
                #pragma unroll
                for (int n = 0; n < 4; ++n)
                    outp[base + n * 16 + c] = f2bf(acc[m][n][r]);
            }
    } else {
        #pragma unroll
        for (int m = 0; m < 4; ++m)
            #pragma unroll
            for (int r = 0; r < 4; ++r) {
                int srow = m0 + wm * 64 + m * 16 + g * 4 + r;
                size_t base = (size_t)srow * DMODEL + n0 + wn * 64;
                #pragma unroll
                for (int n = 0; n < 4; ++n)
                    fo[base + n * 16 + c] = acc[m][n][r];
            }
    }
}

// ---------------- causal flash attention, 64 q-rows x head per block ----------------
// v2: reg-staged prefetch (global loads for tile t+1 issued before compute of
// tile t, LDS write deferred to after the post-compute barrier), descending-qb
// dispatch, head on blockIdx.x (XCD L2 clustering), 2 barriers/tile, setprio
// around MFMA clusters. Per-64-key-tile math identical to the verified r5 kernel.
__global__ __launch_bounds__(256) void attn_kernel(
    const unsigned short* __restrict__ q,
    const unsigned short* __restrict__ k,
    const unsigned short* __restrict__ v,
    unsigned short* __restrict__ ctx) {
    int h = blockIdx.x;                              // head → XCD cluster
    int qb = (int)gridDim.y - 1 - (int)blockIdx.y;   // big blocks dispatch first
    int t = threadIdx.x, w = t >> 6, l = t & 63, g = l >> 4, c = l & 15;

    __shared__ unsigned short Ks[64][72];
    __shared__ unsigned short Vt[64][72];
    __shared__ unsigned short Ps[4][16][72];

    bf16x8 qf[2];
    {
        int qrow = qb * 64 + w * 16 + c;
        const unsigned short* qp = q + (size_t)qrow * DMODEL + h * HDIM + g * 8;
        qf[0] = *(const bf16x8*)qp;
        qf[1] = *(const bf16x8*)(qp + 32);
    }

    f32x4 o[4];
    #pragma unroll
    for (int n = 0; n < 4; ++n) o[n] = (f32x4){0.f, 0.f, 0.f, 0.f};
    float mrow[4] = {-3.0e38f, -3.0e38f, -3.0e38f, -3.0e38f};
    float lsum[4] = {0.f, 0.f, 0.f, 0.f};

    int skr = t >> 2, skc = (t & 3) * 16;
    int svr = t & 63, svc = (t >> 6) * 16;
    const unsigned short* gkb = k + (size_t)skr * DMODEL + h * HDIM + skc;
    const unsigned short* gvb = v + (size_t)svr * DMODEL + h * HDIM + svc;

    int nt = qb + 1;
    u16x8 ka, kb, va, vb;
    // prologue: tile 0 → regs → LDS
    ka = *(const u16x8*)gkb;
    kb = *(const u16x8*)(gkb + 8);
    va = *(const u16x8*)gvb;
    vb = *(const u16x8*)(gvb + 8);
    *(u16x8*)&Ks[skr][skc]     = ka;
    *(u16x8*)&Ks[skr][skc + 8] = kb;
    #pragma unroll
    for (int j = 0; j < 8; ++j) {
        Vt[svc + j][svr]     = va[j];
        Vt[svc + 8 + j][svr] = vb[j];
    }

    for (int kt = 0; kt < nt; ++kt) {
        int kv0 = kt * 64;
        if (kt + 1 < nt) {          // issue next tile's global loads early
            size_t off = (size_t)(kv0 + 64) * DMODEL;
            ka = *(const u16x8*)(gkb + off);
            kb = *(const u16x8*)(gkb + off + 8);
            va = *(const u16x8*)(gvb + off);
            vb = *(const u16x8*)(gvb + off + 8);
        }
        __syncthreads();            // staged LDS for tile kt visible

        // S = Q K^T  (16 q-rows x 64 keys per wave)
        f32x4 sf[4];
        __builtin_amdgcn_s_setprio(1);
        #pragma unroll
        for (int n = 0; n < 4; ++n) {
            sf[n] = (f32x4){0.f, 0.f, 0.f, 0.f};
            #pragma unroll
            for (int ks = 0; ks < 2; ++ks) {
                bf16x8 kf = *(const bf16x8*)&Ks[n * 16 + c][ks * 32 + g * 8];
                sf[n] = __builtin_amdgcn_mfma_f32_16x16x32_bf16(qf[ks], kf, sf[n], 0, 0, 0);
            }
        }
        __builtin_amdgcn_s_setprio(0);

        bool diag = (kt == qb);
        #pragma unroll
        for (int r = 0; r < 4; ++r) {
            int rowg = qb * 64 + w * 16 + g * 4 + r;
            if (diag) {
                #pragma unroll
                for (int n = 0; n < 4; ++n) {
                    int key = kv0 + n * 16 + c;
                    if (key > rowg) sf[n][r] = -3.0e38f;
                }
            }
            float tmax = fmaxf(fmaxf(sf[0][r], sf[1][r]), fmaxf(sf[2][r], sf[3][r]));
            #pragma unroll
            for (int d2 = 1; d2 < 16; d2 <<= 1) tmax = fmaxf(tmax, __shfl_xor(tmax, d2, 64));
            float mnew = fmaxf(mrow[r], tmax);
            float alpha = exp2f((mrow[r] - mnew) * L2E);
            mrow[r] = mnew;
            float psum = 0.f;
            #pragma unroll
            for (int n = 0; n < 4; ++n) {
                float p = exp2f((sf[n][r] - mnew) * L2E);
                sf[n][r] = p;
                psum += p;
            }
            #pragma unroll
            for (int d2 = 1; d2 < 16; d2 <<= 1) psum += __shfl_xor(psum, d2, 64);
            lsum[r] = lsum[r] * alpha + psum;
            #pragma unroll
            for (int n = 0; n < 4; ++n) o[n][r] *= alpha;
        }

        // P: C-layout -> per-wave LDS buffer -> A-layout (wave-local, no barrier)
        #pragma unroll
        for (int n = 0; n < 4; ++n)
            #pragma unroll
            for (int r = 0; r < 4; ++r)
                Ps[w][g * 4 + r][n * 16 + c] = f2bf(sf[n][r]);

        bf16x8 pf0 = *(const bf16x8*)&Ps[w][c][g * 8];
        bf16x8 pf1 = *(const bf16x8*)&Ps[w][c][32 + g * 8];
        __builtin_amdgcn_s_setprio(1);
        #pragma unroll
        for (int n = 0; n < 4; ++n) {
            bf16x8 vf0 = *(const bf16x8*)&Vt[n * 16 + c][g * 8];
            bf16x8 vf1 = *(const bf16x8*)&Vt[n * 16 + c][32 + g * 8];
            o[n] = __builtin_amdgcn_mfma_f32_16x16x32_bf16(pf0, vf0, o[n], 0, 0, 0);
            o[n] = __builtin_amdgcn_mfma_f32_16x16x32_bf16(pf1, vf1, o[n], 0, 0, 0);
        }
        __builtin_amdgcn_s_setprio(0);

        if (kt + 1 < nt) {
            __syncthreads();        // all waves done reading Ks/Vt for tile kt
            *(u16x8*)&Ks[skr][skc]     = ka;
            *(u16x8*)&Ks[skr][skc + 8] = kb;
            #pragma unroll
            for (int j = 0; j < 8; ++j) {
                Vt[svc + j][svr]     = va[j];
                Vt[svc + 8 + j][svr] = vb[j];
            }
        }
    }

    #pragma unroll
    for (int r = 0; r < 4; ++r) {
        float inv = 1.0f / lsum[r];
        int srow = qb * 64 + w * 16 + g * 4 + r;
        size_t base = (size_t)srow * DMODEL + h * HDIM;
        #pragma unroll
        for (int n = 0; n < 4; ++n)
            ctx[base + n * 16 + c] = f2bf(o[n][r] * inv);
    }
}

extern "C" void kernel_launch(void* const* d_in, const int* in_sizes, int n_in,
                              void* d_out, int out_size, void* d_ws, size_t ws_size,
                              hipStream_t stream) {
    const float* x  = (const float*)d_in[0];
    // d_in[1] = causal mask (tril by construction) — unused
    const float* Wq = (const float*)d_in[2];
    const float* Wk = (const float*)d_in[3];
    const float* Wv = (const float*)d_in[4];
    const float* Wo = (const float*)d_in[5];

    // ws layout (peak 35 MB):
    //   [0,0.5M) ctab  [0.5M,1M) stab
    //   [1M,9M)  ctx  (overlays Wtq/Wtk/Wtv, dead after QKV gemm)
    //   [1M,3M) Wtq  [3M,5M) Wtk  [5M,7M) Wtv
    //   [9M,11M) Wto
    //   [11M,19M) kr  [19M,27M) vb  [27M,35M) qr
    char* ws = (char*)d_ws;
    float* ctab = (float*)(ws);
    float* stab = (float*)(ws + (512u << 10));
    unsigned short* ctx = (unsigned short*)(ws + (1u  << 20));
    unsigned short* Wtq = (unsigned short*)(ws + (1u  << 20));
    unsigned short* Wtk = (unsigned short*)(ws + (3u  << 20));
    unsigned short* Wtv = (unsigned short*)(ws + (5u  << 20));
    unsigned short* Wto = (unsigned short*)(ws + (9u  << 20));
    unsigned short* kr  = (unsigned short*)(ws + (11u << 20));
    unsigned short* vb  = (unsigned short*)(ws + (19u << 20));
    unsigned short* qr  = (unsigned short*)(ws + (27u << 20));

    rope_table_kernel<<<(S_LEN * 32) / 256, 256, 0, stream>>>(ctab, stab);
    cvt_wt_kernel<<<dim3(16, 16, 4), 256, 0, stream>>>(Wq, Wk, Wv, Wo, Wtq, Wtk, Wtv, Wto);
    gemm_kernel<1><<<dim3(8, 32, 3), 256, 0, stream>>>(x, nullptr, Wtq, Wtk, Wtv,
                                                       qr, kr, vb, nullptr, ctab, stab);
    attn_kernel<<<dim3(16, 64), 256, 0, stream>>>(qr, kr, vb, ctx);
    gemm_kernel<0><<<dim3(8, 32, 1), 256, 0, stream>>>(nullptr, ctx, Wto, nullptr, nullptr,
                                                       nullptr, nullptr, nullptr,
                                                       (float*)d_out, ctab, stab);
}

// Round 7
// 263.611 us; speedup vs baseline: 1.4565x; 1.0385x over previous
//
#include <hip/hip_runtime.h>
#include <hip/hip_bf16.h>
#include <stdint.h>
#include <stddef.h>

#define S_LEN 4096
#define DMODEL 1024
#define NHEAD 16
#define HDIM 64
#define L2E 1.4426950408889634f

typedef __attribute__((ext_vector_type(8))) short bf16x8;
typedef __attribute__((ext_vector_type(8))) unsigned short u16x8;
typedef __attribute__((ext_vector_type(4))) float f32x4;

__device__ __forceinline__ unsigned short f2bf(float f) {
    unsigned int u = __float_as_uint(f);
    return (unsigned short)((u + 0x7FFFu + ((u >> 16) & 1u)) >> 16);
}

// ---------------- RoPE table: cos/sin [4096][32] ----------------
__global__ __launch_bounds__(256) void rope_table_kernel(float* __restrict__ ctab,
                                                         float* __restrict__ stab) {
    int i = blockIdx.x * 256 + threadIdx.x;
    int s = i >> 5, j = i & 31;
    float freq = exp2f(-0.41524101186092407f * (float)j);   // 10000^(-j/32)
    float ang = (float)s * freq;
    ctab[i] = cosf(ang);
    stab[i] = sinf(ang);
}

// ---------------- W [K][N] f32 -> Wt [N][K] bf16 (transpose) ----------------
__global__ __launch_bounds__(256) void cvt_wt_kernel(
    const float* __restrict__ w0, const float* __restrict__ w1,
    const float* __restrict__ w2, const float* __restrict__ w3,
    unsigned short* __restrict__ t0, unsigned short* __restrict__ t1,
    unsigned short* __restrict__ t2, unsigned short* __restrict__ t3) {
    const float* src; unsigned short* dst;
    switch (blockIdx.z) {
        case 0: src = w0; dst = t0; break;
        case 1: src = w1; dst = t1; break;
        case 2: src = w2; dst = t2; break;
        default: src = w3; dst = t3; break;
    }
    __shared__ float tile[64][65];
    int t = threadIdx.x;
    int k0 = blockIdx.y * 64, n0 = blockIdx.x * 64;
    int r = t >> 2, q4 = (t & 3) * 16;
    const float* sp = src + (size_t)(k0 + r) * DMODEL + n0 + q4;
    #pragma unroll
    for (int j = 0; j < 4; ++j) {
        f32x4 v = *(const f32x4*)(sp + j * 4);
        #pragma unroll
        for (int e = 0; e < 4; ++e) tile[r][q4 + j * 4 + e] = v[e];
    }
    __syncthreads();
    int n = t >> 2, kq = (t & 3) * 16;
    unsigned short* dp = dst + (size_t)(n0 + n) * DMODEL + k0 + kq;
    u16x8 a, b;
    #pragma unroll
    for (int j = 0; j < 8; ++j) { a[j] = f2bf(tile[kq + j][n]); b[j] = f2bf(tile[kq + 8 + j][n]); }
    *(u16x8*)dp = a;
    *(u16x8*)(dp + 8) = b;
}

// ---------------- GEMM 128x128x64, 4 waves, 16x16x32 bf16 MFMA ----------------
// MODE 1: A = f32 (convert in-flight); z in {0,1,2} selects q/k/v output;
//         z<2 RoPE epilogue; z==0 scales by 0.125*L2E (log2-domain scores).
// MODE 0: A = bf16 ctx; f32 store to fo (d_out).
template<int MODE>
__global__ __launch_bounds__(256) void gemm_kernel(
    const float* __restrict__ Af,
    const unsigned short* __restrict__ Ab,
    const unsigned short* __restrict__ B0,
    const unsigned short* __restrict__ B1,
    const unsigned short* __restrict__ B2,
    unsigned short* __restrict__ o0,
    unsigned short* __restrict__ o1,
    unsigned short* __restrict__ o2,
    float* __restrict__ fo,
    const float* __restrict__ ctab,
    const float* __restrict__ stab) {
    int z = blockIdx.z;
    const unsigned short* Bt = (MODE == 0) ? B0 : (z == 0 ? B0 : (z == 1 ? B1 : B2));
    unsigned short* outp     = (MODE == 0) ? o0 : (z == 0 ? o0 : (z == 1 ? o1 : o2));
    int m0 = blockIdx.y * 128, n0 = blockIdx.x * 128;
    __shared__ unsigned short As[128][72];
    __shared__ unsigned short Bs[128][72];
    int t = threadIdx.x, w = t >> 6, l = t & 63;
    int wm = w >> 1, wn = w & 1, g = l >> 4, c = l & 15;

    f32x4 acc[4][4];
    #pragma unroll
    for (int m = 0; m < 4; ++m)
        #pragma unroll
        for (int n = 0; n < 4; ++n) acc[m][n] = (f32x4){0.f, 0.f, 0.f, 0.f};

    int sr = t >> 1, scc = (t & 1) * 32;

    for (int kt = 0; kt < DMODEL; kt += 64) {
        __syncthreads();
        if (MODE == 1) {
            const float* gp = Af + (size_t)(m0 + sr) * DMODEL + kt + scc;
            #pragma unroll
            for (int j = 0; j < 4; ++j) {
                f32x4 lo = *(const f32x4*)(gp + j * 8);
                f32x4 hi = *(const f32x4*)(gp + j * 8 + 4);
                u16x8 o;
                #pragma unroll
                for (int e = 0; e < 4; ++e) { o[e] = f2bf(lo[e]); o[4 + e] = f2bf(hi[e]); }
                *(u16x8*)&As[sr][scc + j * 8] = o;
            }
        } else {
            const unsigned short* gp = Ab + (size_t)(m0 + sr) * DMODEL + kt + scc;
            #pragma unroll
            for (int j = 0; j < 4; ++j)
                *(u16x8*)&As[sr][scc + j * 8] = *(const u16x8*)(gp + j * 8);
        }
        {
            const unsigned short* gp = Bt + (size_t)(n0 + sr) * DMODEL + kt + scc;
            #pragma unroll
            for (int j = 0; j < 4; ++j)
                *(u16x8*)&Bs[sr][scc + j * 8] = *(const u16x8*)(gp + j * 8);
        }
        __syncthreads();
        #pragma unroll
        for (int kk = 0; kk < 64; kk += 32) {
            bf16x8 af[4], bf[4];
            #pragma unroll
            for (int m = 0; m < 4; ++m) af[m] = *(const bf16x8*)&As[wm * 64 + m * 16 + c][kk + g * 8];
            #pragma unroll
            for (int n = 0; n < 4; ++n) bf[n] = *(const bf16x8*)&Bs[wn * 64 + n * 16 + c][kk + g * 8];
            #pragma unroll
            for (int m = 0; m < 4; ++m)
                #pragma unroll
                for (int n = 0; n < 4; ++n)
                    acc[m][n] = __builtin_amdgcn_mfma_f32_16x16x32_bf16(af[m], bf[n], acc[m][n], 0, 0, 0);
        }
    }

    if (MODE == 1 && z < 2) {
        // q: fold 1/sqrt(64) AND log2(e) so attention scores are in log2 domain
        float sc8 = (z == 0) ? 0.125f * L2E : 1.0f;
        #pragma unroll
        for (int m = 0; m < 4; ++m) {
            #pragma unroll
            for (int r = 0; r < 4; ++r) {
                int srow = m0 + wm * 64 + m * 16 + g * 4 + r;
                #pragma unroll
                for (int n = 0; n < 2; ++n) {
                    int e = n * 16 + c;                      // e < 32 within head
                    float cs = ctab[srow * 32 + e];
                    float sn = stab[srow * 32 + e];
                    float lo = acc[m][n][r], hi = acc[m][n + 2][r];
                    float nlo = (lo * cs - hi * sn) * sc8;
                    float nhi = (hi * cs + lo * sn) * sc8;
                    size_t base = (size_t)srow * DMODEL + n0 + wn * 64;
                    outp[base + n * 16 + c]       = f2bf(nlo);
                    outp[base + (n + 2) * 16 + c] = f2bf(nhi);
                }
            }
        }
    } else if (MODE == 1) {
        #pragma unroll
        for (int m = 0; m < 4; ++m)
            #pragma unroll
            for (int r = 0; r < 4; ++r) {
                int srow = m0 + wm * 64 + m * 16 + g * 4 + r;
                size_t base = (size_t)srow * DMODEL + n0 + wn * 64;
                #pragma unroll
                for (int n = 0; n < 4; ++n)
                    outp[base + n * 16 + c] = f2bf(acc[m][n][r]);
            }
    } else {
        #pragma unroll
        for (int m = 0; m < 4; ++m)
            #pragma unroll
            for (int r = 0; r < 4; ++r) {
                int srow = m0 + wm * 64 + m * 16 + g * 4 + r;
                size_t base = (size_t)srow * DMODEL + n0 + wn * 64;
                #pragma unroll
                for (int n = 0; n < 4; ++n)
                    fo[base + n * 16 + c] = acc[m][n][r];
            }
    }
}

// ---------------- causal flash attention, 64 q-rows x head per block ----------------
// v3: scores arrive in log2 domain (L2E folded into q). Defer-max (THR=8),
// truncating bf16 for P with numerator/denominator-consistent psum.
// Reg-staged prefetch + descending-qb + head-major grid as in v2.
__global__ __launch_bounds__(256) void attn_kernel(
    const unsigned short* __restrict__ q,
    const unsigned short* __restrict__ k,
    const unsigned short* __restrict__ v,
    unsigned short* __restrict__ ctx) {
    int h = blockIdx.x;                              // head → XCD cluster
    int qb = (int)gridDim.y - 1 - (int)blockIdx.y;   // big blocks dispatch first
    int t = threadIdx.x, w = t >> 6, l = t & 63, g = l >> 4, c = l & 15;

    __shared__ unsigned short Ks[64][72];
    __shared__ unsigned short Vt[64][72];
    __shared__ unsigned short Ps[4][16][72];

    bf16x8 qf[2];
    {
        int qrow = qb * 64 + w * 16 + c;
        const unsigned short* qp = q + (size_t)qrow * DMODEL + h * HDIM + g * 8;
        qf[0] = *(const bf16x8*)qp;
        qf[1] = *(const bf16x8*)(qp + 32);
    }

    f32x4 o[4];
    #pragma unroll
    for (int n = 0; n < 4; ++n) o[n] = (f32x4){0.f, 0.f, 0.f, 0.f};
    float mrow[4] = {-3.0e38f, -3.0e38f, -3.0e38f, -3.0e38f};
    float lsum[4] = {0.f, 0.f, 0.f, 0.f};

    int skr = t >> 2, skc = (t & 3) * 16;
    int svr = t & 63, svc = (t >> 6) * 16;
    const unsigned short* gkb = k + (size_t)skr * DMODEL + h * HDIM + skc;
    const unsigned short* gvb = v + (size_t)svr * DMODEL + h * HDIM + svc;

    int nt = qb + 1;
    u16x8 ka, kb, va, vb;
    ka = *(const u16x8*)gkb;
    kb = *(const u16x8*)(gkb + 8);
    va = *(const u16x8*)gvb;
    vb = *(const u16x8*)(gvb + 8);
    *(u16x8*)&Ks[skr][skc]     = ka;
    *(u16x8*)&Ks[skr][skc + 8] = kb;
    #pragma unroll
    for (int j = 0; j < 8; ++j) {
        Vt[svc + j][svr]     = va[j];
        Vt[svc + 8 + j][svr] = vb[j];
    }

    for (int kt = 0; kt < nt; ++kt) {
        int kv0 = kt * 64;
        if (kt + 1 < nt) {          // issue next tile's global loads early
            size_t off = (size_t)(kv0 + 64) * DMODEL;
            ka = *(const u16x8*)(gkb + off);
            kb = *(const u16x8*)(gkb + off + 8);
            va = *(const u16x8*)(gvb + off);
            vb = *(const u16x8*)(gvb + off + 8);
        }
        __syncthreads();            // staged LDS for tile kt visible

        // S = Q K^T  (16 q-rows x 64 keys per wave), log2 domain
        f32x4 sf[4];
        __builtin_amdgcn_s_setprio(1);
        #pragma unroll
        for (int n = 0; n < 4; ++n) {
            sf[n] = (f32x4){0.f, 0.f, 0.f, 0.f};
            #pragma unroll
            for (int ks = 0; ks < 2; ++ks) {
                bf16x8 kf = *(const bf16x8*)&Ks[n * 16 + c][ks * 32 + g * 8];
                sf[n] = __builtin_amdgcn_mfma_f32_16x16x32_bf16(qf[ks], kf, sf[n], 0, 0, 0);
            }
        }
        __builtin_amdgcn_s_setprio(0);

        if (kt == qb) {             // diagonal tile: causal mask
            #pragma unroll
            for (int r = 0; r < 4; ++r) {
                int rowg = qb * 64 + w * 16 + g * 4 + r;
                #pragma unroll
                for (int n = 0; n < 4; ++n) {
                    int key = kv0 + n * 16 + c;
                    if (key > rowg) sf[n][r] = -3.0e38f;
                }
            }
        }

        // per-row tile max (16-lane butterfly, masks 1..8 are DPP-cheap)
        float tmax[4];
        #pragma unroll
        for (int r = 0; r < 4; ++r) {
            float tm = fmaxf(fmaxf(sf[0][r], sf[1][r]), fmaxf(sf[2][r], sf[3][r]));
            #pragma unroll
            for (int d2 = 1; d2 < 16; d2 <<= 1) tm = fmaxf(tm, __shfl_xor(tm, d2, 64));
            tmax[r] = tm;
        }
        // defer-max: only rescale when some row grew by > 8 (2^8 in linear)
        bool defer = (tmax[0] <= mrow[0] + 8.f) && (tmax[1] <= mrow[1] + 8.f) &&
                     (tmax[2] <= mrow[2] + 8.f) && (tmax[3] <= mrow[3] + 8.f);
        if (!__all(defer)) {
            #pragma unroll
            for (int r = 0; r < 4; ++r) {
                float mnew = fmaxf(mrow[r], tmax[r]);
                float alpha = exp2f(mrow[r] - mnew);
                mrow[r] = mnew;
                lsum[r] *= alpha;
                #pragma unroll
                for (int n = 0; n < 4; ++n) o[n][r] *= alpha;
            }
        }
        // P = 2^(s-m), truncate to bf16; psum over the truncated values
        #pragma unroll
        for (int r = 0; r < 4; ++r) {
            float psum = 0.f;
            #pragma unroll
            for (int n = 0; n < 4; ++n) {
                float p = exp2f(sf[n][r] - mrow[r]);
                unsigned int pu = __float_as_uint(p);
                Ps[w][g * 4 + r][n * 16 + c] = (unsigned short)(pu >> 16);
                psum += __uint_as_float(pu & 0xFFFF0000u);
            }
            #pragma unroll
            for (int d2 = 1; d2 < 16; d2 <<= 1) psum += __shfl_xor(psum, d2, 64);
            lsum[r] += psum;
        }

        bf16x8 pf0 = *(const bf16x8*)&Ps[w][c][g * 8];
        bf16x8 pf1 = *(const bf16x8*)&Ps[w][c][32 + g * 8];
        __builtin_amdgcn_s_setprio(1);
        #pragma unroll
        for (int n = 0; n < 4; ++n) {
            bf16x8 vf0 = *(const bf16x8*)&Vt[n * 16 + c][g * 8];
            bf16x8 vf1 = *(const bf16x8*)&Vt[n * 16 + c][32 + g * 8];
            o[n] = __builtin_amdgcn_mfma_f32_16x16x32_bf16(pf0, vf0, o[n], 0, 0, 0);
            o[n] = __builtin_amdgcn_mfma_f32_16x16x32_bf16(pf1, vf1, o[n], 0, 0, 0);
        }
        __builtin_amdgcn_s_setprio(0);

        if (kt + 1 < nt) {
            __syncthreads();        // all waves done reading Ks/Vt for tile kt
            *(u16x8*)&Ks[skr][skc]     = ka;
            *(u16x8*)&Ks[skr][skc + 8] = kb;
            #pragma unroll
            for (int j = 0; j < 8; ++j) {
                Vt[svc + j][svr]     = va[j];
                Vt[svc + 8 + j][svr] = vb[j];
            }
        }
    }

    #pragma unroll
    for (int r = 0; r < 4; ++r) {
        float inv = 1.0f / lsum[r];
        int srow = qb * 64 + w * 16 + g * 4 + r;
        size_t base = (size_t)srow * DMODEL + h * HDIM;
        #pragma unroll
        for (int n = 0; n < 4; ++n)
            ctx[base + n * 16 + c] = f2bf(o[n][r] * inv);
    }
}

extern "C" void kernel_launch(void* const* d_in, const int* in_sizes, int n_in,
                              void* d_out, int out_size, void* d_ws, size_t ws_size,
                              hipStream_t stream) {
    const float* x  = (const float*)d_in[0];
    // d_in[1] = causal mask (tril by construction) — unused
    const float* Wq = (const float*)d_in[2];
    const float* Wk = (const float*)d_in[3];
    const float* Wv = (const float*)d_in[4];
    const float* Wo = (const float*)d_in[5];

    // ws layout (peak 35 MB):
    //   [0,0.5M) ctab  [0.5M,1M) stab
    //   [1M,9M)  ctx  (overlays Wtq/Wtk/Wtv, dead after QKV gemm)
    //   [1M,3M) Wtq  [3M,5M) Wtk  [5M,7M) Wtv
    //   [9M,11M) Wto
    //   [11M,19M) kr  [19M,27M) vb  [27M,35M) qr
    char* ws = (char*)d_ws;
    float* ctab = (float*)(ws);
    float* stab = (float*)(ws + (512u << 10));
    unsigned short* ctx = (unsigned short*)(ws + (1u  << 20));
    unsigned short* Wtq = (unsigned short*)(ws + (1u  << 20));
    unsigned short* Wtk = (unsigned short*)(ws + (3u  << 20));
    unsigned short* Wtv = (unsigned short*)(ws + (5u  << 20));
    unsigned short* Wto = (unsigned short*)(ws + (9u  << 20));
    unsigned short* kr  = (unsigned short*)(ws + (11u << 20));
    unsigned short* vb  = (unsigned short*)(ws + (19u << 20));
    unsigned short* qr  = (unsigned short*)(ws + (27u << 20));

    rope_table_kernel<<<(S_LEN * 32) / 256, 256, 0, stream>>>(ctab, stab);
    cvt_wt_kernel<<<dim3(16, 16, 4), 256, 0, stream>>>(Wq, Wk, Wv, Wo, Wtq, Wtk, Wtv, Wto);
    gemm_kernel<1><<<dim3(8, 32, 3), 256, 0, stream>>>(x, nullptr, Wtq, Wtk, Wtv,
                                                       qr, kr, vb, nullptr, ctab, stab);
    attn_kernel<<<dim3(16, 64), 256, 0, stream>>>(qr, kr, vb, ctx);
    gemm_kernel<0><<<dim3(8, 32, 1), 256, 0, stream>>>(nullptr, ctx, Wto, nullptr, nullptr,
                                                       nullptr, nullptr, nullptr,
                                                       (float*)d_out, ctab, stab);
}